// Round 5
// baseline (238.025 us; speedup 1.0000x reference)
//
#include <hip/hip_runtime.h>

#define DIN 256
#define NTOK 4096

typedef __bf16 bf16;
typedef __bf16 bf16x4 __attribute__((ext_vector_type(4)));
typedef __bf16 bf16x8 __attribute__((ext_vector_type(8)));
typedef float floatx16 __attribute__((ext_vector_type(16)));

__device__ inline floatx16 mfma32(bf16x8 a, bf16x8 b, floatx16 c) {
    return __builtin_amdgcn_mfma_f32_32x32x16_bf16(a, b, c, 0, 0, 0);
}

// async global->LDS, 16B per lane. g: per-lane global addr; l: wave-uniform LDS base.
__device__ inline void async16(const void* g, void* l) {
    __builtin_amdgcn_global_load_lds(
        (const __attribute__((address_space(1))) unsigned int*)g,
        (__attribute__((address_space(3))) unsigned int*)l, 16, 0, 0);
}

// ---------------- kernel 1: cast weights to bf16 ----------------
__global__ void convert_w(const float* __restrict__ wq, const float* __restrict__ wk,
                          const float* __restrict__ wv, bf16* __restrict__ Wb) {
    int i = blockIdx.x * 256 + threadIdx.x;   // 0..196607
    const float* src = (i < 65536) ? wq : (i < 131072 ? wk : wv);
    Wb[i] = (bf16)src[i & 65535];
}

// ---------------- kernel 2: QKV projection v3b (unchanged from R4) ----------------
__global__ __launch_bounds__(512, 2) void proj_kernel(
    const float* __restrict__ x, const bf16* __restrict__ Wb,
    bf16* __restrict__ Qo, bf16* __restrict__ Ko, bf16* __restrict__ Vo)
{
    __shared__ __attribute__((aligned(16))) char smem[131072];
    bf16 (*xs)[264] = (bf16(*)[264])smem;
    bf16* bufA = (bf16*)smem;
    bf16* bufB = (bf16*)(smem + 65536);

    int bid = blockIdx.x;
    int b = bid & 7, nt = bid >> 3;
    int n0 = nt * 128;
    int t = threadIdx.x;
    int lane = t & 63, w = t >> 6;
    int l32 = lane & 31, h = lane >> 5;
    int tokg = w >> 1;
    int og   = w & 1;

    int wofs[8];
#pragma unroll
    for (int jj = 0; jj < 8; ++jj) {
        int q = w * 8 + jj;
        int r2 = 2 * q + h;
        int cs = l32 ^ (r2 & 31);
        wofs[jj] = r2 * 512 + cs * 16;
    }

    {
        const float* xb = x + (size_t)b * DIN * NTOK;
#pragma unroll
        for (int it = 0; it < 16; ++it) {
            int flat = it * 512 + t;
            int c = flat >> 5;
            int nf = flat & 31;
            float4 v = *(const float4*)(xb + (size_t)c * NTOK + n0 + nf * 4);
            int nn = nf * 4;
            xs[nn + 0][c] = (bf16)v.x;
            xs[nn + 1][c] = (bf16)v.y;
            xs[nn + 2][c] = (bf16)v.z;
            xs[nn + 3][c] = (bf16)v.w;
        }
    }
    __syncthreads();

    bf16x8 xf[16];
#pragma unroll
    for (int ks = 0; ks < 16; ++ks)
        xf[ks] = *(const bf16x8*)&xs[tokg * 32 + l32][ks * 16 + h * 8];

    __syncthreads();

    {
        const char* src = (const char*)Wb;
#pragma unroll
        for (int jj = 0; jj < 8; ++jj)
            async16(src + wofs[jj], (char*)bufA + (w * 8 + jj) * 1024);
    }
    __syncthreads();

    for (int p = 0; p < 6; ++p) {
        if (p < 5) {
            bf16* nb = ((p + 1) & 1) ? bufB : bufA;
            const char* src = (const char*)Wb + (size_t)(p + 1) * 65536;
#pragma unroll
            for (int jj = 0; jj < 8; ++jj)
                async16(src + wofs[jj], (char*)nb + (w * 8 + jj) * 1024);
        }

        const bf16* wb = (p & 1) ? bufB : bufA;
        int mat = p >> 1, dhalf = p & 1;

        floatx16 acc[2];
#pragma unroll
        for (int dc = 0; dc < 2; ++dc)
#pragma unroll
            for (int i = 0; i < 16; ++i) acc[dc][i] = 0.0f;

        if (mat < 2) {
#pragma unroll
            for (int ks = 0; ks < 16; ++ks) {
#pragma unroll
                for (int dc = 0; dc < 2; ++dc) {
                    int row = og * 64 + dc * 32 + l32;
                    bf16x8 wf = *(const bf16x8*)((const char*)wb + row * 512 +
                                                 (((2 * ks + h) ^ (row & 31)) * 16));
                    acc[dc] = mfma32(xf[ks], wf, acc[dc]);
                }
            }
            bf16* Out = (mat == 0 ? Qo : Ko) + (size_t)b * NTOK * DIN;
#pragma unroll
            for (int dc = 0; dc < 2; ++dc) {
                int d = dhalf * 128 + og * 64 + dc * 32 + l32;
#pragma unroll
                for (int r = 0; r < 16; ++r) {
                    int tok = n0 + tokg * 32 + (r & 3) + 8 * (r >> 2) + 4 * h;
                    Out[(size_t)tok * DIN + d] = (bf16)acc[dc][r];
                }
            }
        } else {
#pragma unroll
            for (int ks = 0; ks < 16; ++ks) {
#pragma unroll
                for (int dc = 0; dc < 2; ++dc) {
                    int row = og * 64 + dc * 32 + l32;
                    bf16x8 wf = *(const bf16x8*)((const char*)wb + row * 512 +
                                                 (((2 * ks + h) ^ (row & 31)) * 16));
                    acc[dc] = mfma32(wf, xf[ks], acc[dc]);
                }
            }
            bf16* Out = Vo + (size_t)b * DIN * NTOK;
            int tok = n0 + tokg * 32 + l32;
#pragma unroll
            for (int dc = 0; dc < 2; ++dc)
#pragma unroll
                for (int r = 0; r < 16; ++r) {
                    int d = dhalf * 128 + og * 64 + dc * 32 + (r & 3) + 8 * (r >> 2) + 4 * h;
                    Out[(size_t)d * NTOK + tok] = (bf16)acc[dc][r];
                }
        }
        __syncthreads();
    }
}

// ---------------- kernel 3: attention v4 — counted-vmcnt pipeline (T3/T4) ----------------
// R4 diagnosis: the per-iter __syncthreads implies s_waitcnt vmcnt(0): the K-DMA
// issued at top of iter mt must land before that iter's own barrier -> ~1600-2000cyc
// drain stall (L2/HBM latency), the structural gap R3's traffic-cut couldn't touch.
// v4: raw s_barrier + counted vmcnt(8) for producers -> K-DMAs get 2 full iters.
// Ks 3-deep (96KB); V global->reg (R3 component, frees the LDS). LDS 128KB.
// Invariant at end of iter i: only tile-(i+3)'s 8 DMAs may remain in flight.
// Producers pre-barrier: vmcnt(8) lgkmcnt(0). Consumers pre-barrier: lgkmcnt(0)
// (Ps lifetime). sched_barrier(0) fences around waits + after barriers (rule #18).
// Tripwire: WRITE_SIZE must stay 32768 KB (jump = spill, R1 lesson).
__global__ __launch_bounds__(512, 2) void attn_kernel(
    const bf16* __restrict__ Q, const bf16* __restrict__ K,
    const bf16* __restrict__ V, float* __restrict__ out)
{
    __shared__ bf16 Ks[3][64][256];   // 96 KB, 3-deep K pipeline
    __shared__ bf16 Ps[2][128][64];   // 32 KB  (total 128 KB)

    int bid = blockIdx.x;
    int b = bid & 7, qt = bid >> 3;   // batch -> XCD L2 locality
    int n0 = qt * 128;
    int t = threadIdx.x, lane = t & 63, w = t >> 6;
    int l32 = lane & 31, h = lane >> 5;
    int lkey = (l32 & 7) ^ ((l32 >> 3) & 3);

    const bf16* Qb = Q + (size_t)b * NTOK * DIN;
    const bf16* Kb = K + (size_t)b * NTOK * DIN;
    const bf16* Vb = V + (size_t)b * DIN * NTOK;
    float* Lp = (float*)&Ps[0][0][0];   // reused AFTER last tile barrier (Ps dead)

    if (w < 4) {
        // ================= S-producer: S^T = K.Q^T =================
        int tokg = w >> 1, mg = w & 1;
        int krow = mg * 32 + l32;

        int koff[8];
#pragma unroll
        for (int jj = 0; jj < 8; ++jj) {
            int q = w * 8 + jj;
            int r = q * 2 + (lane >> 5);
            int ck = (lane & 31) ^ ((r & 7) ^ ((r >> 3) & 3));
            koff[jj] = (r * 256 + ck * 8) * 2;
        }

        bf16x8 qf[2][16];
#pragma unroll
        for (int ca = 0; ca < 2; ++ca) {
            const bf16* qrow = Qb + (size_t)(n0 + tokg * 64 + ca * 32 + l32) * DIN + h * 8;
#pragma unroll
            for (int ks = 0; ks < 16; ++ks) qf[ca][ks] = *(const bf16x8*)(qrow + ks * 16);
        }

        float lsum[2] = {0.0f, 0.0f};

        // prologue: K0->Ks[0], K1->Ks[1], K2->Ks[2]
#pragma unroll
        for (int jj = 0; jj < 8; ++jj)
            async16((const char*)Kb + koff[jj], (bf16*)Ks[0] + (w * 8 + jj) * 512);
#pragma unroll
        for (int jj = 0; jj < 8; ++jj)
            async16((const char*)Kb + 32768 + koff[jj], (bf16*)Ks[1] + (w * 8 + jj) * 512);
#pragma unroll
        for (int jj = 0; jj < 8; ++jj)
            async16((const char*)Kb + 65536 + koff[jj], (bf16*)Ks[2] + (w * 8 + jj) * 512);

        __builtin_amdgcn_sched_barrier(0);
        asm volatile("s_waitcnt vmcnt(16)" ::: "memory");   // K0 landed (K1,K2 fly)
        __builtin_amdgcn_sched_barrier(0);
        __builtin_amdgcn_s_barrier();                       // (A)
        __builtin_amdgcn_sched_barrier(0);

        // compute P0 from Ks[0] -> Ps[0]
        {
            const bf16* Krd = (const bf16*)Ks[0] + krow * 256;
            floatx16 st[2];
#pragma unroll
            for (int i = 0; i < 16; ++i) { st[0][i] = 0.0f; st[1][i] = 0.0f; }
#pragma unroll
            for (int ks = 0; ks < 16; ++ks) {
                bf16x8 kf = *(const bf16x8*)(Krd + (((2 * ks + h) ^ lkey) * 8));
                st[0] = mfma32(kf, qf[0][ks], st[0]);
                st[1] = mfma32(kf, qf[1][ks], st[1]);
            }
#pragma unroll
            for (int ca = 0; ca < 2; ++ca) {
                bf16* Prow = (bf16*)Ps[0] + (tokg * 64 + ca * 32 + l32) * 64;
                float tsum = 0.0f;
#pragma unroll
                for (int g = 0; g < 4; ++g) {
                    bf16x4 pk;
#pragma unroll
                    for (int i = 0; i < 4; ++i) {
                        float e = __expf(st[ca][g * 4 + i] * 0.0625f);
                        tsum += e;
                        pk[i] = (bf16)e;
                    }
                    *(bf16x4*)((char*)Prow + (((mg * 4 + g) ^ lkey) * 16) + h * 8) = pk;
                }
                lsum[ca] += tsum;
            }
        }
        __builtin_amdgcn_sched_barrier(0);
        asm volatile("s_waitcnt vmcnt(8) lgkmcnt(0)" ::: "memory");  // K1 landed
        __builtin_amdgcn_sched_barrier(0);
        __builtin_amdgcn_s_barrier();                       // (B)
        __builtin_amdgcn_sched_barrier(0);

        int br = 1, bd = 0;   // iter i: read Ks[(i+1)%3], DMA into Ks[i%3]
#pragma unroll 1
        for (int i = 0; i < 64; ++i) {
            if (i < 61) {   // DMA K(i+3) -> Ks[bd]
                int kadd = (i + 3) * 32768;
#pragma unroll
                for (int jj = 0; jj < 8; ++jj)
                    async16((const char*)Kb + kadd + koff[jj],
                            (bf16*)Ks[bd] + (w * 8 + jj) * 512);
            }
            if (i < 63) {   // compute P(i+1) from Ks[br] -> Ps[(i+1)&1]
                const bf16* Krd = (const bf16*)Ks[br] + krow * 256;
                floatx16 st[2];
#pragma unroll
                for (int ii = 0; ii < 16; ++ii) { st[0][ii] = 0.0f; st[1][ii] = 0.0f; }
#pragma unroll
                for (int ks = 0; ks < 16; ++ks) {
                    bf16x8 kf = *(const bf16x8*)(Krd + (((2 * ks + h) ^ lkey) * 8));
                    st[0] = mfma32(kf, qf[0][ks], st[0]);
                    st[1] = mfma32(kf, qf[1][ks], st[1]);
                }
                bf16* Pw = (bf16*)Ps[(i + 1) & 1];
#pragma unroll
                for (int ca = 0; ca < 2; ++ca) {
                    bf16* Prow = Pw + (tokg * 64 + ca * 32 + l32) * 64;
                    float tsum = 0.0f;
#pragma unroll
                    for (int g = 0; g < 4; ++g) {
                        bf16x4 pk;
#pragma unroll
                        for (int ii = 0; ii < 4; ++ii) {
                            float e = __expf(st[ca][g * 4 + ii] * 0.0625f);
                            tsum += e;
                            pk[ii] = (bf16)e;
                        }
                        *(bf16x4*)((char*)Prow + (((mg * 4 + g) ^ lkey) * 16) + h * 8) = pk;
                    }
                    lsum[ca] += tsum;
                }
            }
            __builtin_amdgcn_sched_barrier(0);
            asm volatile("s_waitcnt vmcnt(8) lgkmcnt(0)" ::: "memory");
            __builtin_amdgcn_sched_barrier(0);
            __builtin_amdgcn_s_barrier();                   // one barrier per iter
            __builtin_amdgcn_sched_barrier(0);
            bd = br; br = (br == 2) ? 0 : br + 1;
        }

        // epilogue: h-pair reduce, publish row sums (Ps now dead -> Lp alias ok)
#pragma unroll
        for (int ca = 0; ca < 2; ++ca) {
            float sv = lsum[ca];
            sv += __shfl_xor(sv, 32);
            if (h == 0) Lp[mg * 128 + tokg * 64 + ca * 32 + l32] = sv;
        }
        __syncthreads();   // (3)
    } else {
        // ====== PV-consumer: O^T = V^T.P^T ; V global(L2)->reg, dbuf (R3 component) ======
        int slab = w - 4;

        const bf16* Vr0 = Vb + (size_t)(slab * 64 + l32) * NTOK + h * 8;
        const bf16* Vr1 = Vb + (size_t)(slab * 64 + 32 + l32) * NTOK + h * 8;

        floatx16 oacc[8];   // [dc*4+tc]
#pragma unroll
        for (int i = 0; i < 8; ++i)
            for (int j = 0; j < 16; ++j) oacc[i][j] = 0.0f;

        bf16x8 vaA[8], vaB[8];   // [dc*4+kst]
#pragma unroll
        for (int kst = 0; kst < 4; ++kst) {
            vaA[kst]     = *(const bf16x8*)(Vr0 + kst * 16);
            vaA[4 + kst] = *(const bf16x8*)(Vr1 + kst * 16);
        }
        __builtin_amdgcn_s_barrier();                       // (A)
        __builtin_amdgcn_sched_barrier(0);
        __builtin_amdgcn_s_barrier();                       // (B)
        __builtin_amdgcn_sched_barrier(0);

#pragma unroll 1
        for (int j = 0; j < 32; ++j) {
            int i = 2 * j;
            // ---- body A: tile i (Ps[0], vaA); prefetch V(i+1) -> vaB ----
            {
                int nn = (i + 1) * 64;
#pragma unroll
                for (int kst = 0; kst < 4; ++kst) {
                    vaB[kst]     = *(const bf16x8*)(Vr0 + nn + kst * 16);
                    vaB[4 + kst] = *(const bf16x8*)(Vr1 + nn + kst * 16);
                }
                const char* Prd = (const char*)Ps[0];
#pragma unroll
                for (int kst = 0; kst < 4; ++kst) {
                    bf16x8 pb[4];
#pragma unroll
                    for (int tc = 0; tc < 4; ++tc)
                        pb[tc] = *(const bf16x8*)(Prd + (tc * 32 + l32) * 128 +
                                                  (((kst * 2 + h) ^ lkey) * 16));
#pragma unroll
                    for (int tc = 0; tc < 4; ++tc) {
                        oacc[tc]     = mfma32(vaA[kst],     pb[tc], oacc[tc]);
                        oacc[4 + tc] = mfma32(vaA[4 + kst], pb[tc], oacc[4 + tc]);
                    }
                }
                __builtin_amdgcn_sched_barrier(0);
                asm volatile("s_waitcnt lgkmcnt(0)" ::: "memory");
                __builtin_amdgcn_sched_barrier(0);
                __builtin_amdgcn_s_barrier();
                __builtin_amdgcn_sched_barrier(0);
            }
            // ---- body B: tile i+1 (Ps[1], vaB); prefetch V(i+2) -> vaA ----
            {
                if (j < 31) {
                    int nn = (i + 2) * 64;
#pragma unroll
                    for (int kst = 0; kst < 4; ++kst) {
                        vaA[kst]     = *(const bf16x8*)(Vr0 + nn + kst * 16);
                        vaA[4 + kst] = *(const bf16x8*)(Vr1 + nn + kst * 16);
                    }
                }
                const char* Prd = (const char*)Ps[1];
#pragma unroll
                for (int kst = 0; kst < 4; ++kst) {
                    bf16x8 pb[4];
#pragma unroll
                    for (int tc = 0; tc < 4; ++tc)
                        pb[tc] = *(const bf16x8*)(Prd + (tc * 32 + l32) * 128 +
                                                  (((kst * 2 + h) ^ lkey) * 16));
#pragma unroll
                    for (int tc = 0; tc < 4; ++tc) {
                        oacc[tc]     = mfma32(vaB[kst],     pb[tc], oacc[tc]);
                        oacc[4 + tc] = mfma32(vaB[4 + kst], pb[tc], oacc[4 + tc]);
                    }
                }
                __builtin_amdgcn_sched_barrier(0);
                asm volatile("s_waitcnt lgkmcnt(0)" ::: "memory");
                __builtin_amdgcn_sched_barrier(0);
                __builtin_amdgcn_s_barrier();
                __builtin_amdgcn_sched_barrier(0);
            }
        }

        __syncthreads();   // (3): Lp ready
        float* ob = out + (size_t)b * DIN * NTOK;
#pragma unroll
        for (int tc = 0; tc < 4; ++tc) {
            int tok = tc * 32 + l32;
            float rinv = 1.0f / (Lp[tok] + Lp[128 + tok]);
#pragma unroll
            for (int dc = 0; dc < 2; ++dc)
#pragma unroll
                for (int r = 0; r < 16; ++r) {
                    int d = slab * 64 + dc * 32 + (r & 3) + 8 * (r >> 2) + 4 * h;
                    ob[(size_t)d * NTOK + n0 + tok] = oacc[dc * 4 + tc][r] * rinv;
                }
        }
    }
}

// ---------------- launcher ----------------
extern "C" void kernel_launch(void* const* d_in, const int* in_sizes, int n_in,
                              void* d_out, int out_size, void* d_ws, size_t ws_size,
                              hipStream_t stream) {
    const float* x  = (const float*)d_in[0];
    const float* wq = (const float*)d_in[1];
    const float* wk = (const float*)d_in[2];
    const float* wv = (const float*)d_in[3];
    float* outf = (float*)d_out;

    char* ws = (char*)d_ws;
    bf16* Wb = (bf16*)(ws);                                  // 384 KB
    bf16* Qp = (bf16*)(ws + (1u << 20));                     // 16 MB
    bf16* Kp = (bf16*)(ws + (1u << 20) + (16u << 20));       // 16 MB
    bf16* Vp = (bf16*)(ws + (1u << 20) + (32u << 20));       // 16 MB

    convert_w<<<768, 256, 0, stream>>>(wq, wk, wv, Wb);
    proj_kernel<<<256, 512, 0, stream>>>(x, Wb, Qp, Kp, Vp);
    attn_kernel<<<256, 512, 0, stream>>>(Qp, Kp, Vp, outf);
}